// Round 9
// baseline (115.997 us; speedup 1.0000x reference)
//
#include <hip/hip_runtime.h>
#include <math.h>

typedef unsigned long long u64;
typedef unsigned int u32;
typedef float f4 __attribute__((ext_vector_type(4)));

#define HH 512
#define WW 512
#define CC 64
#define HWHW (HH * WW)
#define NBOX 30
#define KTOP 10
#define NBLK 256                 // worker blocks per batch
#define CPB (NBLK * KTOP)        // 2560 candidates per batch

// ---------------- Kernel 1: intensity = sqrt(sum_c loc^2); zero sync words ------
// 512 blocks x 256 threads; each thread owns TWO float4 pixel-quads (4KB apart).
__global__ void k_intensity(const float* __restrict__ loc, float* __restrict__ inten,
                            u32* __restrict__ flags, int* __restrict__ done, int B) {
    int t   = threadIdx.x;
    int blk = blockIdx.x;
    if (blk < B) {                      // blocks 0..B-1 zero the B*256 flags
        flags[blk * NBLK + t] = 0;
        if (blk == 0 && t == 0) *done = 0;
    }
    int b = blk >> 7;                   // 128 blocks per batch
    int j = blk & 127;
    const f4* base = reinterpret_cast<const f4*>(loc + (size_t)b * CC * HWHW);
    int q0 = j * 512 + t;
    int q1 = q0 + 256;

    f4 s0 = {0.f, 0.f, 0.f, 0.f};
    f4 s1 = {0.f, 0.f, 0.f, 0.f};
    #pragma unroll 8
    for (int c = 0; c < CC; ++c) {
        const f4* p = base + (size_t)c * (HWHW / 4);
        f4 v0 = __builtin_nontemporal_load(p + q0);
        f4 v1 = __builtin_nontemporal_load(p + q1);
        s0 += v0 * v0;
        s1 += v1 * v1;
    }
    f4 o0, o1;
    o0[0] = sqrtf(s0[0]); o0[1] = sqrtf(s0[1]); o0[2] = sqrtf(s0[2]); o0[3] = sqrtf(s0[3]);
    o1[0] = sqrtf(s1[0]); o1[1] = sqrtf(s1[1]); o1[2] = sqrtf(s1[2]); o1[3] = sqrtf(s1[3]);
    f4* out = reinterpret_cast<f4*>(inten + (size_t)b * HWHW);
    out[q0] = o0;
    out[q1] = o1;
}

// ---------------- Kernel 2 (fused): peaks -> flags -> loss -> final mean --------
// grid = B*256 worker blocks + B loss blocks (loss blocks have the HIGHEST ids,
// so they are dispatched last -> no deadlock even without co-residency).
__global__ void k_fused(const float* __restrict__ loc, const float* __restrict__ det,
                        const float* __restrict__ boxes, const float* __restrict__ inten,
                        u64* __restrict__ cand, u32* __restrict__ flags,
                        int* __restrict__ done, float* __restrict__ bloss,
                        float* __restrict__ out, int B) {
    __shared__ u64 shl[1664];            // workers: pool[1024] + smb[64][10]
    int t    = threadIdx.x;
    int lane = t & 63;
    int wid  = t >> 6;
    int blk  = blockIdx.x;

    if (blk < B * NBLK) {
        // ================= worker: peak detect + compact + wave0 top-10 =========
        int b    = blk >> 8;
        int pblk = blk & 255;
        const float* I = inten + (size_t)b * HWHW;
        int pix0 = pblk * 1024 + t * 4;  // never crosses a row (512%4==0)
        int y  = pix0 >> 9;
        int x0 = pix0 & (WW - 1);

        float w00,w01,w02,w03,w04,w05, w10,w11,w12,w13,w14,w15, w20,w21,w22,w23,w24,w25;
        {
            bool r0 = (y - 1) >= 0, r2 = (y + 1) < HH;
            bool c0 = (x0 - 1) >= 0, c5 = (x0 + 4) < WW;
            const float* Rm = I + (y - 1) * WW + x0;
            const float* Rc = I + y * WW + x0;
            const float* Rp = I + (y + 1) * WW + x0;
            w00 = (r0 && c0) ? Rm[-1] : -INFINITY;
            w01 = r0 ? Rm[0] : -INFINITY;  w02 = r0 ? Rm[1] : -INFINITY;
            w03 = r0 ? Rm[2] : -INFINITY;  w04 = r0 ? Rm[3] : -INFINITY;
            w05 = (r0 && c5) ? Rm[4] : -INFINITY;
            w10 = c0 ? Rc[-1] : -INFINITY;
            w11 = Rc[0]; w12 = Rc[1]; w13 = Rc[2]; w14 = Rc[3];
            w15 = c5 ? Rc[4] : -INFINITY;
            w20 = (r2 && c0) ? Rp[-1] : -INFINITY;
            w21 = r2 ? Rp[0] : -INFINITY;  w22 = r2 ? Rp[1] : -INFINITY;
            w23 = r2 ? Rp[2] : -INFINITY;  w24 = r2 ? Rp[3] : -INFINITY;
            w25 = (r2 && c5) ? Rp[4] : -INFINITY;
        }

        u64 k0, k1, k2, k3;
        {
            float m, v;
            v = w11;
            m = fmaxf(fmaxf(fmaxf(w00, w01), fmaxf(w02, w10)),
                      fmaxf(fmaxf(w11, w12), fmaxf(fmaxf(w20, w21), w22)));
            k0 = (v > 0.5f && v == m) ? (((u64)(__float_as_uint(v) | 0x80000000u) << 32) | (u32)(~(u32)(pix0 + 0))) : 0ull;
            v = w12;
            m = fmaxf(fmaxf(fmaxf(w01, w02), fmaxf(w03, w11)),
                      fmaxf(fmaxf(w12, w13), fmaxf(fmaxf(w21, w22), w23)));
            k1 = (v > 0.5f && v == m) ? (((u64)(__float_as_uint(v) | 0x80000000u) << 32) | (u32)(~(u32)(pix0 + 1))) : 0ull;
            v = w13;
            m = fmaxf(fmaxf(fmaxf(w02, w03), fmaxf(w04, w12)),
                      fmaxf(fmaxf(w13, w14), fmaxf(fmaxf(w22, w23), w24)));
            k2 = (v > 0.5f && v == m) ? (((u64)(__float_as_uint(v) | 0x80000000u) << 32) | (u32)(~(u32)(pix0 + 2))) : 0ull;
            v = w14;
            m = fmaxf(fmaxf(fmaxf(w03, w04), fmaxf(w05, w13)),
                      fmaxf(fmaxf(w14, w15), fmaxf(fmaxf(w23, w24), w25)));
            k3 = (v > 0.5f && v == m) ? (((u64)(__float_as_uint(v) | 0x80000000u) << 32) | (u32)(~(u32)(pix0 + 3))) : 0ull;
        }

        u64 a[4]; int n = 0;
        if (k0) a[n++] = k0;
        if (k1) a[n++] = k1;
        if (k2) a[n++] = k2;
        if (k3) a[n++] = k3;

        __shared__ int cnt;
        if (t == 0) cnt = 0;
        __syncthreads();

        int incl = n;
        #pragma unroll
        for (int s = 1; s < 64; s <<= 1) {
            int o = __shfl_up(incl, s, 64);
            if (lane >= s) incl += o;
        }
        int excl = incl - n;
        int wtot = __shfl(incl, 63, 64);
        int base = 0;
        if (lane == 0 && wtot > 0) base = atomicAdd(&cnt, wtot);
        base = __shfl(base, 0, 64);
        for (int i = 0; i < n; ++i) shl[base + excl + i] = a[i];   // pool = shl[0..1023]
        __syncthreads();

        int total = cnt;
        if (t < 64) {
            u64 lv[KTOP];
            #pragma unroll
            for (int i = 0; i < KTOP; ++i) lv[i] = 0ull;
            for (int j = lane; j < total; j += 64) {
                u64 v = shl[j];
                if (v > lv[KTOP - 1]) {
                    lv[KTOP - 1] = v;
                    #pragma unroll
                    for (int m = KTOP - 1; m > 0; --m)
                        if (lv[m] > lv[m - 1]) { u64 tm = lv[m]; lv[m] = lv[m - 1]; lv[m - 1] = tm; }
                }
            }
            // 10 rounds of wave argmax + pop
            u64 mine = 0;
            #pragma unroll
            for (int r = 0; r < KTOP; ++r) {
                u64 wv = lv[0];
                #pragma unroll
                for (int s = 1; s < 64; s <<= 1) {
                    u64 o = __shfl_xor(wv, s, 64);
                    wv = (o > wv) ? o : wv;
                }
                if (lane == r) mine = wv;
                if (lv[0] == wv && wv != 0ull) {
                    #pragma unroll
                    for (int m = 0; m < KTOP - 1; ++m) lv[m] = lv[m + 1];
                    lv[KTOP - 1] = 0ull;
                }
            }
            if (lane < KTOP)
                cand[(size_t)b * CPB + pblk * KTOP + lane] = mine;
            if (lane == 0) {
                __threadfence();     // drain this wave's cand stores, make visible
                __hip_atomic_store(&flags[b * NBLK + pblk], 1u,
                                   __ATOMIC_RELEASE, __HIP_MEMORY_SCOPE_AGENT);
            }
        }
    } else {
        // ================= loss block (one per batch) ===========================
        int b = blk - B * NBLK;
        __shared__ int s_cx[NBOX], s_cy[NBOX], s_static[NBOX];
        __shared__ float pf[KTOP][CC], df[NBOX][CC], invn[NBOX + KTOP];
        __shared__ float hv[256], hc[256];
        __shared__ u64 sc[40], stopk[KTOP];
        __shared__ int topi[KTOP], tvalid[KTOP];

        // --- prefetch phase (independent of peaks): boxes + det gathers + norms ---
        if (t < NBOX) {
            const float* bx = boxes + ((size_t)b * NBOX + t) * 8;
            float fx = (bx[0] + 59.9f) / 119.8f * 512.0f;
            float fy = (bx[1] + 59.9f) / 119.8f * 512.0f;
            int cx = (int)fx; int cy = (int)fy;        // trunc == astype(int32)
            cx = min(max(cx, 0), WW - 1);
            cy = min(max(cy, 0), HH - 1);
            s_cx[t] = cx; s_cy[t] = cy;
            s_static[t] = (bx[7] == 0.0f) ? 1 : 0;
        }
        __syncthreads();
        #pragma unroll
        for (int w = 0; w < 8; ++w) {
            int e = t + w * 256;
            if (e < NBOX * CC) {
                int n = e >> 6, c = e & 63;
                int pix = s_cy[n] * WW + s_cx[n];
                df[n][c] = det[((size_t)b * CC + c) * HWHW + pix];
            }
        }
        __syncthreads();
        if (t < NBOX) {
            float s = 0.f;
            for (int c = 0; c < CC; ++c) s += df[t][c] * df[t][c];
            invn[t] = 1.0f / fmaxf(sqrtf(s), 1e-8f);
        }
        __syncthreads();
        for (int e = t; e < NBOX * CC; e += 256) { int n = e >> 6; df[n][e & 63] *= invn[n]; }

        // --- spin until all 256 worker blocks of this batch have published ---
        int rdy;
        do {
            u32 f = __hip_atomic_load(&flags[b * NBLK + t],
                                      __ATOMIC_ACQUIRE, __HIP_MEMORY_SCOPE_AGENT);
            rdy = (f != 0);
        } while (!__syncthreads_and(rdy));
        __threadfence();

        // --- per-thread top-10 over 10 coalesced candidates ---
        u64 lv[KTOP];
        #pragma unroll
        for (int i = 0; i < KTOP; ++i) lv[i] = 0ull;
        const u64* C = cand + (size_t)b * CPB;
        #pragma unroll
        for (int w = 0; w < CPB / 256; ++w) {
            u64 v = C[t + w * 256];
            if (v > lv[KTOP - 1]) {
                lv[KTOP - 1] = v;
                #pragma unroll
                for (int m = KTOP - 1; m > 0; --m)
                    if (lv[m] > lv[m - 1]) { u64 tm = lv[m]; lv[m] = lv[m - 1]; lv[m - 1] = tm; }
            }
        }

        // --- stage 1: per-wave top-10 via shuffle argmax + pop ---
        u64 wmine = 0;
        #pragma unroll
        for (int r = 0; r < KTOP; ++r) {
            u64 wv = lv[0];
            #pragma unroll
            for (int s = 1; s < 64; s <<= 1) {
                u64 o = __shfl_xor(wv, s, 64);
                wv = (o > wv) ? o : wv;
            }
            if (lane == r) wmine = wv;
            if (lv[0] == wv && wv != 0ull) {
                #pragma unroll
                for (int m = 0; m < KTOP - 1; ++m) lv[m] = lv[m + 1];
                lv[KTOP - 1] = 0ull;
            }
        }
        if (lane < KTOP) sc[wid * KTOP + lane] = wmine;
        __syncthreads();

        // --- stage 2: wave 0 merges the 40 survivors ---
        if (t < 64) {
            u64 v = (t < 40) ? sc[t] : 0ull;
            u64 fm = 0;
            #pragma unroll
            for (int r = 0; r < KTOP; ++r) {
                u64 wv = v;
                #pragma unroll
                for (int s = 1; s < 64; s <<= 1) {
                    u64 o = __shfl_xor(wv, s, 64);
                    wv = (o > wv) ? o : wv;
                }
                if (t == r) fm = wv;
                if (v == wv && wv != 0ull) v = 0ull;
            }
            if (t < KTOP) stopk[t] = fm;
        }
        __syncthreads();

        if (t < KTOP) {
            u64 kk = stopk[t];
            tvalid[t] = (kk != 0ull) ? 1 : 0;
            topi[t] = (int)((~(u32)kk) & (HWHW - 1));
        }
        __syncthreads();

        // --- loc gathers for peak features ---
        #pragma unroll
        for (int w = 0; w < 3; ++w) {
            int e = t + w * 256;
            if (e < KTOP * CC) {
                int k = e >> 6, c = e & 63;
                int pix = tvalid[k] ? topi[k] : 0;
                pf[k][c] = loc[((size_t)b * CC + c) * HWHW + pix];
            }
        }
        __syncthreads();
        if (t < KTOP) {
            float s = 0.f;
            for (int c = 0; c < CC; ++c) s += pf[t][c] * pf[t][c];
            invn[NBOX + t] = 1.0f / fmaxf(sqrtf(s), 1e-8f);
        }
        __syncthreads();
        for (int e = t; e < KTOP * CC; e += 256) { int k = e >> 6; pf[k][e & 63] *= invn[NBOX + k]; }
        __syncthreads();

        // --- sim + masked relu-margin mean ---
        float lsum = 0.f, cntp = 0.f;
        for (int p = t; p < NBOX * KTOP; p += 256) {
            int n = p / KTOP, k = p - n * KTOP;
            float dot = 0.f;
            for (int c = 0; c < CC; ++c) dot += df[n][c] * pf[k][c];
            if (s_static[n] && tvalid[k]) {
                float r = dot - 0.5f;
                if (r > 0.f) lsum += r;
                cntp += 1.f;
            }
        }
        hv[t] = lsum; hc[t] = cntp;
        __syncthreads();
        for (int s = 128; s > 0; s >>= 1) {
            if (t < s) { hv[t] += hv[t + s]; hc[t] += hc[t + s]; }
            __syncthreads();
        }
        if (t == 0) {
            float np = hc[0];
            bloss[b] = (np > 0.f) ? hv[0] / fmaxf(np, 1.0f) : 0.f;
            __threadfence();
            int old = atomicAdd(done, 1);
            if (old == B - 1) {
                __threadfence();
                float s = 0.f;
                for (int i = 0; i < B; ++i) s += bloss[i];
                out[0] = s / (float)B;
            }
        }
    }
}

extern "C" void kernel_launch(void* const* d_in, const int* in_sizes, int n_in,
                              void* d_out, int out_size, void* d_ws, size_t ws_size,
                              hipStream_t stream) {
    const float* loc   = (const float*)d_in[0];
    const float* det   = (const float*)d_in[1];
    const float* boxes = (const float*)d_in[2];
    float* out = (float*)d_out;

    int B = in_sizes[0] / (CC * HWHW);   // 4

    // workspace layout (8-byte alignment maintained)
    float* inten = (float*)d_ws;                          // B*HW floats (4 MB)
    u64*   cand  = (u64*)(inten + (size_t)B * HWHW);      // B*2560 u64
    u32*   flags = (u32*)(cand + (size_t)B * CPB);        // B*256 u32
    int*   done  = (int*)(flags + (size_t)B * NBLK);      // 1 int
    float* bloss = (float*)(done + 2);                    // B floats

    dim3 blk(256);
    hipLaunchKernelGGL(k_intensity, dim3(B * 128), blk, 0, stream, loc, inten, flags, done, B);
    hipLaunchKernelGGL(k_fused, dim3(B * NBLK + B), blk, 0, stream,
                       loc, det, boxes, inten, cand, flags, done, bloss, out, B);
}

// Round 10
// 72.334 us; speedup vs baseline: 1.6036x; 1.6036x over previous
//
#include <hip/hip_runtime.h>
#include <math.h>

typedef unsigned long long u64;
typedef unsigned int u32;
typedef float f4 __attribute__((ext_vector_type(4)));

#define HH 512
#define WW 512
#define CC 64
#define HWHW (HH * WW)
#define NBOX 30
#define KTOP 10
#define BLKS_PER_B 256
#define CAND_PER_BATCH (BLKS_PER_B * KTOP)   // 2560

// ---------------- Kernel 1: intensity = sqrt(sum_c loc^2); zero out[0] ----------
// 512 blocks x 256 threads; each thread owns TWO float4 pixel-quads (4KB apart).
// Nontemporal loads: loc is read-once.
__global__ void k_intensity(const float* __restrict__ loc, float* __restrict__ inten,
                            float* __restrict__ out) {
    int t   = threadIdx.x;
    int blk = blockIdx.x;
    if (blk == 0 && t == 0) out[0] = 0.f;   // ordered before k_loss by kernel boundary
    int b   = blk >> 7;               // 128 blocks per batch
    int j   = blk & 127;
    const f4* base = reinterpret_cast<const f4*>(loc + (size_t)b * CC * HWHW);
    int q0 = j * 512 + t;             // quad indices (float4 units)
    int q1 = q0 + 256;

    f4 s0 = {0.f, 0.f, 0.f, 0.f};
    f4 s1 = {0.f, 0.f, 0.f, 0.f};
    #pragma unroll 8
    for (int c = 0; c < CC; ++c) {
        const f4* p = base + (size_t)c * (HWHW / 4);
        f4 v0 = __builtin_nontemporal_load(p + q0);
        f4 v1 = __builtin_nontemporal_load(p + q1);
        s0 += v0 * v0;
        s1 += v1 * v1;
    }
    f4 o0, o1;
    o0[0] = sqrtf(s0[0]); o0[1] = sqrtf(s0[1]); o0[2] = sqrtf(s0[2]); o0[3] = sqrtf(s0[3]);
    o1[0] = sqrtf(s1[0]); o1[1] = sqrtf(s1[1]); o1[2] = sqrtf(s1[2]); o1[3] = sqrtf(s1[3]);
    f4* outp = reinterpret_cast<f4*>(inten + (size_t)b * HWHW);
    outp[q0] = o0;
    outp[q1] = o1;
}

// ---------------- Kernel 2: peak detect + block compaction + 1-wave top-10 ------
// grid = B*256 blocks of 256 threads; each thread tests 4 consecutive pixels.
// key = (monotone_val_bits << 32) | ~pix  -> u64 compare == (val desc, idx asc).
__global__ void k_peakblock(const float* __restrict__ inten, u64* __restrict__ cand) {
    int t    = threadIdx.x;
    int lane = t & 63;
    int blk  = blockIdx.x;
    int b    = blk >> 8;              // 256 blocks per batch
    int pblk = blk & 255;
    const float* I = inten + (size_t)b * HWHW;
    int pix0 = pblk * 1024 + t * 4;   // 4-aligned, never crosses a row (512%4==0)
    int y  = pix0 >> 9;
    int x0 = pix0 & (WW - 1);

    // 3x6 neighborhood window (rows y-1..y+1, cols x0-1..x0+4), OOB -> -inf
    float w00,w01,w02,w03,w04,w05, w10,w11,w12,w13,w14,w15, w20,w21,w22,w23,w24,w25;
    {
        bool r0 = (y - 1) >= 0, r2 = (y + 1) < HH;
        bool c0 = (x0 - 1) >= 0, c5 = (x0 + 4) < WW;
        const float* Rm = I + (y - 1) * WW + x0;
        const float* Rc = I + y * WW + x0;
        const float* Rp = I + (y + 1) * WW + x0;
        w00 = (r0 && c0) ? Rm[-1] : -INFINITY;
        w01 = r0 ? Rm[0] : -INFINITY;  w02 = r0 ? Rm[1] : -INFINITY;
        w03 = r0 ? Rm[2] : -INFINITY;  w04 = r0 ? Rm[3] : -INFINITY;
        w05 = (r0 && c5) ? Rm[4] : -INFINITY;
        w10 = c0 ? Rc[-1] : -INFINITY;
        w11 = Rc[0]; w12 = Rc[1]; w13 = Rc[2]; w14 = Rc[3];
        w15 = c5 ? Rc[4] : -INFINITY;
        w20 = (r2 && c0) ? Rp[-1] : -INFINITY;
        w21 = r2 ? Rp[0] : -INFINITY;  w22 = r2 ? Rp[1] : -INFINITY;
        w23 = r2 ? Rp[2] : -INFINITY;  w24 = r2 ? Rp[3] : -INFINITY;
        w25 = (r2 && c5) ? Rp[4] : -INFINITY;
    }

    u64 k0, k1, k2, k3;
    {
        float m, v;
        v = w11;
        m = fmaxf(fmaxf(fmaxf(w00, w01), fmaxf(w02, w10)),
                  fmaxf(fmaxf(w11, w12), fmaxf(fmaxf(w20, w21), w22)));
        k0 = (v > 0.5f && v == m) ? (((u64)(__float_as_uint(v) | 0x80000000u) << 32) | (u32)(~(u32)(pix0 + 0))) : 0ull;
        v = w12;
        m = fmaxf(fmaxf(fmaxf(w01, w02), fmaxf(w03, w11)),
                  fmaxf(fmaxf(w12, w13), fmaxf(fmaxf(w21, w22), w23)));
        k1 = (v > 0.5f && v == m) ? (((u64)(__float_as_uint(v) | 0x80000000u) << 32) | (u32)(~(u32)(pix0 + 1))) : 0ull;
        v = w13;
        m = fmaxf(fmaxf(fmaxf(w02, w03), fmaxf(w04, w12)),
                  fmaxf(fmaxf(w13, w14), fmaxf(fmaxf(w22, w23), w24)));
        k2 = (v > 0.5f && v == m) ? (((u64)(__float_as_uint(v) | 0x80000000u) << 32) | (u32)(~(u32)(pix0 + 2))) : 0ull;
        v = w14;
        m = fmaxf(fmaxf(fmaxf(w03, w04), fmaxf(w05, w13)),
                  fmaxf(fmaxf(w14, w15), fmaxf(fmaxf(w23, w24), w25)));
        k3 = (v > 0.5f && v == m) ? (((u64)(__float_as_uint(v) | 0x80000000u) << 32) | (u32)(~(u32)(pix0 + 3))) : 0ull;
    }

    // compact nonzero keys of this thread
    u64 a[4]; int n = 0;
    if (k0) a[n++] = k0;
    if (k1) a[n++] = k1;
    if (k2) a[n++] = k2;
    if (k3) a[n++] = k3;

    __shared__ int cnt;
    __shared__ u64 pool[1024];
    if (t == 0) cnt = 0;
    __syncthreads();

    // wave-level exclusive prefix scan of n + one LDS atomic per wave
    int incl = n;
    #pragma unroll
    for (int s = 1; s < 64; s <<= 1) {
        int o = __shfl_up(incl, s, 64);
        if (lane >= s) incl += o;
    }
    int excl = incl - n;
    int wtot = __shfl(incl, 63, 64);
    int base = 0;
    if (lane == 0 && wtot > 0) base = atomicAdd(&cnt, wtot);
    base = __shfl(base, 0, 64);
    for (int i = 0; i < n; ++i) pool[base + excl + i] = a[i];
    __syncthreads();

    int total = cnt;
    if (t < 64) {
        // per-lane sorted top-10 over pool (<=16 strided entries/lane)
        u64 lv[KTOP];
        #pragma unroll
        for (int i = 0; i < KTOP; ++i) lv[i] = 0ull;
        for (int j = lane; j < total; j += 64) {
            u64 v = pool[j];
            if (v > lv[KTOP - 1]) {
                lv[KTOP - 1] = v;
                #pragma unroll
                for (int m = KTOP - 1; m > 0; --m)
                    if (lv[m] > lv[m - 1]) { u64 tm = lv[m]; lv[m] = lv[m - 1]; lv[m - 1] = tm; }
            }
        }
        // 10 rounds of wave argmax + pop
        u64 mine = 0;
        #pragma unroll
        for (int r = 0; r < KTOP; ++r) {
            u64 wv = lv[0];
            #pragma unroll
            for (int s = 1; s < 64; s <<= 1) {
                u64 o = __shfl_xor(wv, s, 64);
                wv = (o > wv) ? o : wv;
            }
            if (lane == r) mine = wv;
            if (lv[0] == wv && wv != 0ull) {
                #pragma unroll
                for (int m = 0; m < KTOP - 1; ++m) lv[m] = lv[m + 1];
                lv[KTOP - 1] = 0ull;
            }
        }
        if (lane < KTOP)
            cand[(size_t)b * CAND_PER_BATCH + pblk * KTOP + lane] = mine;
    }
}

// ---------------- Kernel 3: global top-10 + gather + cosine loss + mean ---------
// grid = B blocks of 256 threads; each block atomically adds loss_b/B into out.
__global__ void k_loss(const float* __restrict__ loc, const float* __restrict__ det,
                       const float* __restrict__ boxes,
                       const u64* __restrict__ cand,
                       float* __restrict__ out, int B) {
    int b = blockIdx.x;
    int t = threadIdx.x;
    int lane = t & 63;

    // --- per-thread top-10 over 10 candidates (u64 compare == total order) ---
    u64 lv[KTOP];
    #pragma unroll
    for (int i = 0; i < KTOP; ++i) lv[i] = 0ull;
    const u64* C = cand + (size_t)b * CAND_PER_BATCH;
    #pragma unroll
    for (int w = 0; w < CAND_PER_BATCH / 256; ++w) {
        u64 v = C[t + w * 256];
        if (v > lv[KTOP - 1]) {
            lv[KTOP - 1] = v;
            #pragma unroll
            for (int m = KTOP - 1; m > 0; --m)
                if (lv[m] > lv[m - 1]) { u64 tm = lv[m]; lv[m] = lv[m - 1]; lv[m - 1] = tm; }
        }
    }

    // --- stage 1: per-wave top-10 via shuffle argmax + pop ---
    __shared__ u64 sc[40];
    __shared__ u64 stopk[KTOP];
    u64 wmine = 0;
    #pragma unroll
    for (int r = 0; r < KTOP; ++r) {
        u64 wv = lv[0];
        #pragma unroll
        for (int s = 1; s < 64; s <<= 1) {
            u64 o = __shfl_xor(wv, s, 64);
            wv = (o > wv) ? o : wv;
        }
        if (lane == r) wmine = wv;
        if (lv[0] == wv && wv != 0ull) {
            #pragma unroll
            for (int m = 0; m < KTOP - 1; ++m) lv[m] = lv[m + 1];
            lv[KTOP - 1] = 0ull;
        }
    }
    if (lane < KTOP) sc[(t >> 6) * KTOP + lane] = wmine;
    __syncthreads();

    // --- stage 2: wave 0 merges the 40 survivors ---
    if (t < 64) {
        u64 v = (t < 40) ? sc[t] : 0ull;
        u64 fm = 0;
        #pragma unroll
        for (int r = 0; r < KTOP; ++r) {
            u64 wv = v;
            #pragma unroll
            for (int s = 1; s < 64; s <<= 1) {
                u64 o = __shfl_xor(wv, s, 64);
                wv = (o > wv) ? o : wv;
            }
            if (t == r) fm = wv;
            if (v == wv && wv != 0ull) v = 0ull;
        }
        if (t < KTOP) stopk[t] = fm;
    }
    __syncthreads();

    // --- decode top-10 ---
    __shared__ int topi[KTOP], tvalid[KTOP];
    if (t < KTOP) {
        u64 kk = stopk[t];
        tvalid[t] = (kk != 0ull) ? 1 : 0;
        topi[t] = (int)((~(u32)kk) & (HWHW - 1));
    }

    // --- box centers + static mask ---
    __shared__ int s_cx[NBOX], s_cy[NBOX], s_static[NBOX];
    if (t < NBOX) {
        const float* bx = boxes + ((size_t)b * NBOX + t) * 8;
        float fx = (bx[0] + 59.9f) / 119.8f * 512.0f;
        float fy = (bx[1] + 59.9f) / 119.8f * 512.0f;
        int cx = (int)fx; int cy = (int)fy;            // trunc == astype(int32)
        cx = min(max(cx, 0), WW - 1);
        cy = min(max(cy, 0), HH - 1);
        s_cx[t] = cx; s_cy[t] = cy;
        s_static[t] = (bx[7] == 0.0f) ? 1 : 0;
    }
    __syncthreads();

    // --- gathers ---
    __shared__ float pf[KTOP][CC];
    __shared__ float df[NBOX][CC];
    #pragma unroll
    for (int w = 0; w < 3; ++w) {
        int e = t + w * 256;
        if (e < KTOP * CC) {
            int k = e >> 6, c = e & 63;
            int pix = tvalid[k] ? topi[k] : 0;
            pf[k][c] = loc[((size_t)b * CC + c) * HWHW + pix];
        }
    }
    #pragma unroll
    for (int w = 0; w < 8; ++w) {
        int e = t + w * 256;
        if (e < NBOX * CC) {
            int n = e >> 6, c = e & 63;
            int pix = s_cy[n] * WW + s_cx[n];
            df[n][c] = det[((size_t)b * CC + c) * HWHW + pix];
        }
    }
    __syncthreads();

    // --- torch-eps cosine normalization ---
    __shared__ float invn[NBOX + KTOP];
    if (t < NBOX + KTOP) {
        float s = 0.f;
        if (t < NBOX) {
            for (int c = 0; c < CC; ++c) s += df[t][c] * df[t][c];
        } else {
            int k = t - NBOX;
            for (int c = 0; c < CC; ++c) s += pf[k][c] * pf[k][c];
        }
        invn[t] = 1.0f / fmaxf(sqrtf(s), 1e-8f);
    }
    __syncthreads();
    for (int e = t; e < NBOX * CC; e += 256) { int n = e >> 6; df[n][e & 63] *= invn[n]; }
    for (int e = t; e < KTOP * CC; e += 256) { int k = e >> 6; pf[k][e & 63] *= invn[NBOX + k]; }
    __syncthreads();

    // --- sim + masked relu-margin mean ---
    float lsum = 0.f, cntp = 0.f;
    for (int p = t; p < NBOX * KTOP; p += 256) {
        int n = p / KTOP, k = p - n * KTOP;
        float dot = 0.f;
        for (int c = 0; c < CC; ++c) dot += df[n][c] * pf[k][c];
        if (s_static[n] && tvalid[k]) {
            float r = dot - 0.5f;
            if (r > 0.f) lsum += r;
            cntp += 1.f;
        }
    }
    __shared__ float hv[256];
    __shared__ float hc[256];
    hv[t] = lsum; hc[t] = cntp;
    __syncthreads();
    for (int s = 128; s > 0; s >>= 1) {
        if (t < s) { hv[t] += hv[t + s]; hc[t] += hc[t + s]; }
        __syncthreads();
    }
    if (t == 0) {
        float np = hc[0];
        float lb = (np > 0.f) ? hv[0] / fmaxf(np, 1.0f) : 0.f;
        atomicAdd(out, lb / (float)B);   // 4 uncontended adds; out zeroed by k_intensity
    }
}

extern "C" void kernel_launch(void* const* d_in, const int* in_sizes, int n_in,
                              void* d_out, int out_size, void* d_ws, size_t ws_size,
                              hipStream_t stream) {
    const float* loc   = (const float*)d_in[0];
    const float* det   = (const float*)d_in[1];
    const float* boxes = (const float*)d_in[2];
    float* out = (float*)d_out;

    int B = in_sizes[0] / (CC * HWHW);   // 4

    // workspace layout
    float* inten = (float*)d_ws;                          // B*HW floats (4 MB)
    u64*   cand  = (u64*)(inten + (size_t)B * HWHW);      // B*2560 u64 (8-byte aligned)

    dim3 blk(256);
    hipLaunchKernelGGL(k_intensity, dim3(B * 128), blk, 0, stream, loc, inten, out);
    hipLaunchKernelGGL(k_peakblock, dim3(B * BLKS_PER_B), blk, 0, stream, inten, cand);
    hipLaunchKernelGGL(k_loss, dim3(B), blk, 0, stream, loc, det, boxes, cand, out, B);
}